// Round 1
// baseline (553.412 us; speedup 1.0000x reference)
//
#include <hip/hip_runtime.h>
#include <stdint.h>

// ---------------------------------------------------------------------------
// out[n_tok, out_f] = input @ (w_scale * round(weight))^T + b_scale*round(bias)
// M=8192, N=4096, K=4096, fp32 in/out.
//
// R5: escape the m97-structure ~900 TF plateau (MfmaUtil 39, barrier-drain
// ~45%) via the 256^2 8-phase template (T1+T3+T4+T5):
//   - 256x256 tile, BK=64, 8 waves (512 thr), 32x32x16 MFMA, acc 4x2/wave
//   - 128 KiB LDS double-buffer, raw s_barrier (no vmcnt(0) drain)
//   - counted s_waitcnt vmcnt(8): this iteration's 8 stage-loads stay in
//     flight across the barrier; drain to 0 only once at t+2==NT
//   - setprio(1) around each 8-MFMA cluster; bijective XCD blockIdx swizzle
// Safety: all ds_reads of tile t are lgkm(0)-complete in every wave before
// the mid-barrier; only after it do we issue tile t+2 stages into the same
// buffer. Tile t+1 is guaranteed landed by end-of-iter vmcnt(8)+barrier.
// NOTE: SQ_LDS_BANK_CONFLICT was saturated at 2^25 in R4 (stale "0 conflict"
// comment) — re-read it this round now that the drain no longer shadows LDS.
// ---------------------------------------------------------------------------

using bf16x8   = __attribute__((ext_vector_type(8))) __bf16;
using floatx16 = __attribute__((ext_vector_type(16))) float;
using us8      = __attribute__((ext_vector_type(8))) unsigned short;
using us4      = __attribute__((ext_vector_type(4))) unsigned short;

__device__ __forceinline__ unsigned short f2bf_rne(float x) {
    unsigned int u = __float_as_uint(x);
    return (unsigned short)((u + 0x7fffu + ((u >> 16) & 1u)) >> 16);
}

__device__ __forceinline__ void stage16(const unsigned short* g, unsigned short* l) {
    __builtin_amdgcn_global_load_lds(
        (__attribute__((address_space(1))) void*)g,
        (__attribute__((address_space(3))) void*)l,
        16, 0, 0);
}

// ---------------------------------------------------------------------------
// Fused fp32->bf16 conversion: A (identity) then B (rintf). Coalesced 16B/lane.
// ---------------------------------------------------------------------------
__global__ __launch_bounds__(256) void cvt_both(
    const float* __restrict__ inA, unsigned short* __restrict__ outA, long long nA4,
    const float* __restrict__ inB, unsigned short* __restrict__ outB, long long nB4) {
    const long long i = (long long)blockIdx.x * 256 + threadIdx.x;
    if (i < nA4) {
        float4 v = ((const float4*)inA)[i];
        us4 o = { f2bf_rne(v.x), f2bf_rne(v.y), f2bf_rne(v.z), f2bf_rne(v.w) };
        ((us4*)outA)[i] = o;
    } else {
        const long long j = i - nA4;
        if (j < nB4) {
            float4 v = ((const float4*)inB)[j];
            us4 o = { f2bf_rne(rintf(v.x)), f2bf_rne(rintf(v.y)),
                      f2bf_rne(rintf(v.z)), f2bf_rne(rintf(v.w)) };
            ((us4*)outB)[j] = o;
        }
    }
}

// ---------------------------------------------------------------------------
// 256x256 8-phase bf16 GEMM, B^T layout. Block=512 (8 waves, 2Mx4N).
// Wave -> 128x64 output; 4x2 grid of 32x32x16 MFMA accumulators.
// LDS per matrix per buffer: [256][64] shorts (32 KiB); slot s of row r
// holds global k-chunk s ^ (r&7) (16B chunks, 8/row). Stage src pre-swizzled,
// LDS dest linear (gload_lds requirement).
// ---------------------------------------------------------------------------
__global__ __launch_bounds__(512) void gemm256_8ph(
    const unsigned short* __restrict__ A,   // [M][K] bf16
    const unsigned short* __restrict__ B,   // [N][K] bf16 (exact ints)
    const float* __restrict__ bias,
    const float* __restrict__ wscale_p,
    const float* __restrict__ bscale_p,
    float* __restrict__ C,                  // [M][N] fp32
    int M, int N, int K) {
    constexpr int BK   = 64;
    constexpr int TILE = 256 * BK;              // shorts per matrix per buffer
    __shared__ unsigned short ldsA[2 * TILE];   // 64 KiB
    __shared__ unsigned short ldsB[2 * TILE];   // 64 KiB

    const int tid  = threadIdx.x;
    const int wave = tid >> 6;
    const int lane = tid & 63;

    // bijective XCD swizzle (host guarantees gridDim.x % 8 == 0)
    const int nbx = N >> 8;
    int wg;
    {
        const int cpx = (int)gridDim.x >> 3;
        wg = ((int)blockIdx.x & 7) * cpx + ((int)blockIdx.x >> 3);
    }
    const int bm = (wg / nbx) << 8;
    const int bn = (wg % nbx) << 8;

    const int wm    = (wave >> 2) << 7;   // 0 / 128
    const int wn    = (wave & 3) << 6;    // 0/64/128/192
    const int col   = lane & 31;
    const int khalf = lane >> 5;

    // ---- staging addressing: 2048 chunks/matrix/tile; round i (64 rows):
    // thread covers chunk c = i*512 + tid -> row = c>>3, slot = tid&7,
    // holds global chunk g = (tid&7) ^ (row&7) = (tid&7) ^ ((tid>>3)&7).
    const int row512 = tid >> 3;                           // 0..63
    const int gk = ((tid & 7) ^ (row512 & 7)) << 3;        // shorts
    const unsigned short* gA = A + (size_t)(bm + row512) * K + gk;
    const unsigned short* gB = B + (size_t)(bn + row512) * K + gk;
    unsigned short* sA = ldsA + (wave << 9);               // wave-uniform base
    unsigned short* sB = ldsB + (wave << 9);

    // ---- fragment read offsets (rows of A/B tile; r&7 == col&7)
    int rowA[4], rowB[2], slotv[4];
#pragma unroll
    for (int mi = 0; mi < 4; ++mi) rowA[mi] = (wm + mi * 32 + col) << 6;
#pragma unroll
    for (int ni = 0; ni < 2; ++ni) rowB[ni] = (wn + ni * 32 + col) << 6;
#pragma unroll
    for (int ks = 0; ks < 4; ++ks) slotv[ks] = ((ks * 2 + khalf) ^ (col & 7)) << 3;

    const float wsc = wscale_p[0];
    const float bsc = bscale_p[0];
    float badd[2];
#pragma unroll
    for (int ni = 0; ni < 2; ++ni)
        badd[ni] = bsc * rintf(bias[bn + wn + ni * 32 + col]);

    const int NT = K >> 6;

    // ---- prologue: stage tile 0 -> buf0, tile 1 -> buf1 (8 loads each)
#pragma unroll
    for (int i = 0; i < 4; ++i) {
        stage16(gA + (size_t)(i * 64) * K,      sA + i * 4096);
        stage16(gB + (size_t)(i * 64) * K,      sB + i * 4096);
    }
#pragma unroll
    for (int i = 0; i < 4; ++i) {
        stage16(gA + (size_t)(i * 64) * K + 64, sA + TILE + i * 4096);
        stage16(gB + (size_t)(i * 64) * K + 64, sB + TILE + i * 4096);
    }
    asm volatile("s_waitcnt vmcnt(8)" ::: "memory");   // tile 0 landed
    __builtin_amdgcn_s_barrier();
    __builtin_amdgcn_sched_barrier(0);

    floatx16 acc[4][2] = {};

#define READ_KS(ks, ar, br)                                                       \
    {                                                                             \
        const int so = slotv[ks];                                                 \
        _Pragma("unroll") for (int mi = 0; mi < 4; ++mi)                          \
            ar[mi] = __builtin_bit_cast(bf16x8, *(const us8*)&SA[rowA[mi] + so]); \
        _Pragma("unroll") for (int ni = 0; ni < 2; ++ni)                          \
            br[ni] = __builtin_bit_cast(bf16x8, *(const us8*)&SB[rowB[ni] + so]); \
    }

#define MFMA8(ar, br)                                                             \
    __builtin_amdgcn_s_setprio(1);                                                \
    _Pragma("unroll") for (int mi = 0; mi < 4; ++mi)                              \
        _Pragma("unroll") for (int ni = 0; ni < 2; ++ni)                          \
            acc[mi][ni] = __builtin_amdgcn_mfma_f32_32x32x16_bf16(                \
                ar[mi], br[ni], acc[mi][ni], 0, 0, 0);                            \
    __builtin_amdgcn_s_setprio(0);

    for (int t = 0; t < NT; ++t) {
        const unsigned short* SA = ldsA + (t & 1) * TILE;
        const unsigned short* SB = ldsB + (t & 1) * TILE;
        unsigned short* dA = sA + (t & 1) * TILE;
        unsigned short* dB = sB + (t & 1) * TILE;
        const size_t kt2 = (size_t)(t + 2) * BK;
        const bool do_stage = (t + 2 < NT);

        bf16x8 a0[4], a1[4], a2[4], a3[4];
        bf16x8 b0[2], b1[2], b2[2], b3[2];

        // phase A: read ks0,ks1; mfma ks0
        READ_KS(0, a0, b0)
        READ_KS(1, a1, b1)
        MFMA8(a0, b0)
        __builtin_amdgcn_sched_barrier(0);

        // phase B: read ks2,ks3; mfma ks1
        READ_KS(2, a2, b2)
        READ_KS(3, a3, b3)
        MFMA8(a1, b1)

        // mid barrier: every wave's reads of this buffer are complete after
        // this point -> safe to overwrite with tile t+2 stages.
        asm volatile("s_waitcnt lgkmcnt(0)" ::: "memory");
        __builtin_amdgcn_sched_barrier(0);
        __builtin_amdgcn_s_barrier();
        __builtin_amdgcn_sched_barrier(0);

        // phase C: stage rounds 0,1 of tile t+2; mfma ks2
        if (do_stage) {
#pragma unroll
            for (int i = 0; i < 2; ++i) {
                stage16(gA + (size_t)(i * 64) * K + kt2, dA + i * 4096);
                stage16(gB + (size_t)(i * 64) * K + kt2, dB + i * 4096);
            }
        }
        MFMA8(a2, b2)
        __builtin_amdgcn_sched_barrier(0);

        // phase D: stage rounds 2,3 of tile t+2; mfma ks3
        if (do_stage) {
#pragma unroll
            for (int i = 2; i < 4; ++i) {
                stage16(gA + (size_t)(i * 64) * K + kt2, dA + i * 4096);
                stage16(gB + (size_t)(i * 64) * K + kt2, dB + i * 4096);
            }
        }
        MFMA8(a3, b3)
        __builtin_amdgcn_sched_barrier(0);

        // end-of-iter: tile t+1 must be landed before next iteration reads it.
        // Counted wait: this iteration's own 8 stages may stay in flight.
        if (do_stage)         { asm volatile("s_waitcnt vmcnt(8)" ::: "memory"); }
        else if (t + 2 == NT) { asm volatile("s_waitcnt vmcnt(0)" ::: "memory"); }
        __builtin_amdgcn_s_barrier();
        __builtin_amdgcn_sched_barrier(0);
    }

#undef READ_KS
#undef MFMA8

    // Epilogue. 32x32 C/D layout (m74/m101): col = lane&31,
    // row = (reg&3) + 8*(reg>>2) + 4*(lane>>5).
    const int rb = khalf << 2;
#pragma unroll
    for (int mi = 0; mi < 4; ++mi) {
#pragma unroll
        for (int ni = 0; ni < 2; ++ni) {
            const int n = bn + wn + ni * 32 + col;
#pragma unroll
            for (int reg = 0; reg < 16; ++reg) {
                const int m = bm + wm + mi * 32 + (reg & 3) + 8 * (reg >> 2) + rb;
                C[(size_t)m * N + n] = acc[mi][ni][reg] * wsc + badd[ni];
            }
        }
    }
}

// ---------------------------------------------------------------------------
// R4 kernel kept as fallback for shapes not divisible by 256.
// bf16 GEMM, B^T layout. Block=256 (4 waves), tile 128x128, BK=64.
// ---------------------------------------------------------------------------
__global__ __launch_bounds__(256) void gemm_bf16_bt(
    const unsigned short* __restrict__ A,
    const unsigned short* __restrict__ B,
    const float* __restrict__ bias,
    const float* __restrict__ wscale_p,
    const float* __restrict__ bscale_p,
    float* __restrict__ C,
    int M, int N, int K) {
    constexpr int BM = 128, BK = 64;
    __shared__ unsigned short ldsA[BM * BK];
    __shared__ unsigned short ldsB[BM * BK];

    const int tid  = threadIdx.x;
    const int wave = tid >> 6;
    const int lane = tid & 63;

    const int bm = blockIdx.y * BM;
    const int bn = blockIdx.x * BM;
    const int wm = (wave >> 1) * 64;
    const int wn = (wave & 1) * 64;

    const float wsc = wscale_p[0];
    const float bsc = bscale_p[0];

    const int col = lane & 31;
    const int khalf = lane >> 5;

    float badd[2];
#pragma unroll
    for (int ni = 0; ni < 2; ++ni)
        badd[ni] = bsc * rintf(bias[bn + wn + ni * 32 + col]);

    const int g_st = ((lane & 7) ^ (lane >> 3)) * 8;
    const unsigned short* gAp[4];
    const unsigned short* gBp[4];
    unsigned short* lA[4];
    unsigned short* lB[4];
#pragma unroll
    for (int i = 0; i < 4; ++i) {
        const int r = wave * 32 + i * 8 + (lane >> 3);
        gAp[i] = A + (size_t)(bm + r) * K + g_st;
        gBp[i] = B + (size_t)(bn + r) * K + g_st;
        lA[i] = &ldsA[(wave * 256 + i * 64) * 8];
        lB[i] = &ldsB[(wave * 256 + i * 64) * 8];
    }

    floatx16 acc[2][2] = {};

    for (int kt = 0; kt < K; kt += BK) {
#pragma unroll
        for (int i = 0; i < 4; ++i) {
            stage16(gAp[i] + kt, lA[i]);
            stage16(gBp[i] + kt, lB[i]);
        }
        __syncthreads();

#pragma unroll
        for (int ks = 0; ks < 4; ++ks) {
            const int gc = ks * 2 + khalf;
            const int slot = (gc ^ (lane & 7)) * 8;
            bf16x8 af[2], bfr[2];
#pragma unroll
            for (int mi = 0; mi < 2; ++mi) {
                const int off = (wm + mi * 32 + col) * BK + slot;
                af[mi] = __builtin_bit_cast(bf16x8, *(const us8*)&ldsA[off]);
            }
#pragma unroll
            for (int ni = 0; ni < 2; ++ni) {
                const int off = (wn + ni * 32 + col) * BK + slot;
                bfr[ni] = __builtin_bit_cast(bf16x8, *(const us8*)&ldsB[off]);
            }
#pragma unroll
            for (int mi = 0; mi < 2; ++mi)
#pragma unroll
                for (int ni = 0; ni < 2; ++ni)
                    acc[mi][ni] = __builtin_amdgcn_mfma_f32_32x32x16_bf16(
                        af[mi], bfr[ni], acc[mi][ni], 0, 0, 0);
        }
        __syncthreads();
    }

    const int rbase = 4 * khalf;
#pragma unroll
    for (int mi = 0; mi < 2; ++mi) {
#pragma unroll
        for (int ni = 0; ni < 2; ++ni) {
            const int n = bn + wn + ni * 32 + col;
#pragma unroll
            for (int reg = 0; reg < 16; ++reg) {
                const int m = bm + wm + mi * 32 + (reg & 3) + 8 * (reg >> 2) + rbase;
                C[(size_t)m * N + n] = acc[mi][ni][reg] * wsc + badd[ni];
            }
        }
    }
}

// ---------------------------------------------------------------------------
// Last-resort fallback (d_ws too small — not expected).
// ---------------------------------------------------------------------------
__global__ __launch_bounds__(256) void fallback_gemm(
    const float* __restrict__ A, const float* __restrict__ W,
    const float* __restrict__ bias, const float* __restrict__ wsp,
    const float* __restrict__ bsp, float* __restrict__ C, int M, int N, int K) {
    const int n = blockIdx.x * 256 + threadIdx.x;
    const int m = blockIdx.y;
    if (n >= N || m >= M) return;
    float s = 0.f;
    for (int k = 0; k < K; ++k)
        s += A[(size_t)m * K + k] * rintf(W[(size_t)n * K + k]);
    C[(size_t)m * N + n] = s * wsp[0] + bsp[0] * rintf(bias[n]);
}

extern "C" void kernel_launch(void* const* d_in, const int* in_sizes, int n_in,
                              void* d_out, int out_size, void* d_ws, size_t ws_size,
                              hipStream_t stream) {
    const float* input  = (const float*)d_in[0];
    const float* weight = (const float*)d_in[1];
    const float* bias   = (const float*)d_in[2];
    const float* wscale = (const float*)d_in[3];
    const float* bscale = (const float*)d_in[4];
    float* out = (float*)d_out;

    const int N = in_sizes[2];
    const int K = in_sizes[1] / N;
    const int M = in_sizes[0] / K;

    const size_t needA = (size_t)M * K * sizeof(unsigned short);
    const size_t needB = (size_t)N * K * sizeof(unsigned short);

    if (ws_size >= needA + needB && (M % 128) == 0 && (N % 128) == 0 &&
        (K % 64) == 0) {
        unsigned short* Abf = (unsigned short*)d_ws;
        unsigned short* Bbf = (unsigned short*)((char*)d_ws + needA);
        const long long nA4 = (long long)M * K / 4;
        const long long nB4 = (long long)N * K / 4;
        const long long nthr = nA4 + nB4;
        cvt_both<<<(unsigned)((nthr + 255) / 256), 256, 0, stream>>>(
            input, Abf, nA4, weight, Bbf, nB4);

        const int nwg256 = (M / 256) * (N / 256);
        if ((M % 256) == 0 && (N % 256) == 0 && (K / 64) >= 4 &&
            (nwg256 % 8) == 0) {
            gemm256_8ph<<<dim3(nwg256), 512, 0, stream>>>(
                Abf, Bbf, bias, wscale, bscale, out, M, N, K);
        } else {
            dim3 grid(N / 128, M / 128);
            gemm_bf16_bt<<<grid, 256, 0, stream>>>(Abf, Bbf, bias, wscale,
                                                   bscale, out, M, N, K);
        }
    } else {
        dim3 grid((N + 255) / 256, M);
        fallback_gemm<<<grid, 256, 0, stream>>>(input, weight, bias, wscale, bscale, out, M, N, K);
    }
}

// Round 2
// 550.964 us; speedup vs baseline: 1.0044x; 1.0044x over previous
//
#include <hip/hip_runtime.h>
#include <stdint.h>

// ---------------------------------------------------------------------------
// out[n_tok, out_f] = input @ (w_scale * round(weight))^T + b_scale*round(bias)
// M=8192, N=4096, K=4096, fp32 in/out.
//
// R6: R5's "8-phase" was phase-shaped but pipe-serial: all 24 ds_reads were
// issued before the mid-barrier and the last 16 MFMAs ran LDS-silent ->
// LDS(2300cy) + MFMA(2066cy) ran back-to-back (5800cy/K-tile measured,
// MfmaUtil 39%). True m201 structure: 2 barriers PER PHASE, each phase =
// {4-8 ds_read + 0-4 stage + barrier + lgkm(0) + 8 MFMA + [vmcnt] + barrier},
// so wave-stagger overlaps LDS and MFMA pipes in every phase.
//   - phase p = (mi-pair, ks-pair): p0=mi01/ks01, p1=mi01/ks23,
//     p2=mi23/ks01, p3=mi23/ks23. B frags loaded in p0/p1, held in regs.
//   - prefetch depth-1 into the DEAD buffer (t+1 -> buf (t+1)&1; its t-1
//     data died at t-1's end barrier) -> no overwrite hazard.
//   - deadline-ordered stages: p0: Ab0,Ab2,Bb0,Bb1; p1: Bb2,Bb3; p3: Ab1,Ab3.
//   - counted waits: vmcnt(6) end-p1 (gates p2's reads of Ab1/Ab3, staged
//     t-1 p3); vmcnt(2) end-p3 (allows own Ab1/Ab3 stages in flight across
//     the tile boundary). vmcnt BEFORE barrier => cross-wave visibility.
// Bank conflicts: 2.52e7 (~4 cy/b128) with the chunk^(row&7) swizzle --
// acceptable for now; revisit if MfmaUtil plateaus ~55%.
// ---------------------------------------------------------------------------

using bf16x8   = __attribute__((ext_vector_type(8))) __bf16;
using floatx16 = __attribute__((ext_vector_type(16))) float;
using us8      = __attribute__((ext_vector_type(8))) unsigned short;
using us4      = __attribute__((ext_vector_type(4))) unsigned short;

__device__ __forceinline__ unsigned short f2bf_rne(float x) {
    unsigned int u = __float_as_uint(x);
    return (unsigned short)((u + 0x7fffu + ((u >> 16) & 1u)) >> 16);
}

__device__ __forceinline__ void stage16(const unsigned short* g, unsigned short* l) {
    __builtin_amdgcn_global_load_lds(
        (__attribute__((address_space(1))) void*)g,
        (__attribute__((address_space(3))) void*)l,
        16, 0, 0);
}

// ---------------------------------------------------------------------------
// Fused fp32->bf16 conversion: A (identity) then B (rintf). Coalesced 16B/lane.
// ---------------------------------------------------------------------------
__global__ __launch_bounds__(256) void cvt_both(
    const float* __restrict__ inA, unsigned short* __restrict__ outA, long long nA4,
    const float* __restrict__ inB, unsigned short* __restrict__ outB, long long nB4) {
    const long long i = (long long)blockIdx.x * 256 + threadIdx.x;
    if (i < nA4) {
        float4 v = ((const float4*)inA)[i];
        us4 o = { f2bf_rne(v.x), f2bf_rne(v.y), f2bf_rne(v.z), f2bf_rne(v.w) };
        ((us4*)outA)[i] = o;
    } else {
        const long long j = i - nA4;
        if (j < nB4) {
            float4 v = ((const float4*)inB)[j];
            us4 o = { f2bf_rne(rintf(v.x)), f2bf_rne(rintf(v.y)),
                      f2bf_rne(rintf(v.z)), f2bf_rne(rintf(v.w)) };
            ((us4*)outB)[j] = o;
        }
    }
}

// ---------------------------------------------------------------------------
// 256x256 phase-paired bf16 GEMM, B^T layout. Block=512 (8 waves, 2Mx4N).
// Wave -> 128x64 output; 4x2 grid of 32x32x16 MFMA accumulators.
// LDS per matrix per buffer: [256][64] shorts (32 KiB); slot s of row r
// holds global k-chunk s ^ (r&7) (16B chunks, 8/row). Stage src pre-swizzled,
// LDS dest linear (gload_lds requirement).
// Stage unit = 64-row block of one matrix (1 gload_lds per wave, 8 waves).
// ---------------------------------------------------------------------------
__global__ __launch_bounds__(512) void gemm256_ph(
    const unsigned short* __restrict__ A,   // [M][K] bf16
    const unsigned short* __restrict__ B,   // [N][K] bf16 (exact ints)
    const float* __restrict__ bias,
    const float* __restrict__ wscale_p,
    const float* __restrict__ bscale_p,
    float* __restrict__ C,                  // [M][N] fp32
    int M, int N, int K) {
    constexpr int BK   = 64;
    constexpr int TILE = 256 * BK;              // shorts per matrix per buffer
    __shared__ unsigned short ldsA[2 * TILE];   // 64 KiB
    __shared__ unsigned short ldsB[2 * TILE];   // 64 KiB

    const int tid  = threadIdx.x;
    const int wave = tid >> 6;
    const int lane = tid & 63;

    // bijective XCD swizzle (host guarantees gridDim.x % 8 == 0)
    const int nbx = N >> 8;
    int wg;
    {
        const int cpx = (int)gridDim.x >> 3;
        wg = ((int)blockIdx.x & 7) * cpx + ((int)blockIdx.x >> 3);
    }
    const int bm = (wg / nbx) << 8;
    const int bn = (wg % nbx) << 8;

    const int wm    = (wave >> 2) << 7;   // 0 / 128
    const int wn    = (wave & 3) << 6;    // 0/64/128/192
    const int col   = lane & 31;
    const int khalf = lane >> 5;

    // ---- staging addressing: thread covers chunk (row=tid>>3, slot=tid&7)
    // of each 64-row block; holds global k-chunk (tid&7)^((tid>>3)&7).
    const int row512 = tid >> 3;                           // 0..63
    const int gk = ((tid & 7) ^ (row512 & 7)) << 3;        // shorts
    const unsigned short* gA = A + (size_t)(bm + row512) * K + gk;
    const unsigned short* gB = B + (size_t)(bn + row512) * K + gk;
    unsigned short* sA = ldsA + (wave << 9);               // wave-uniform base
    unsigned short* sB = ldsB + (wave << 9);

    // ---- fragment read offsets (rows of A/B tile; r&7 == col&7)
    int rowA[4], rowB[2], slotv[4];
#pragma unroll
    for (int mi = 0; mi < 4; ++mi) rowA[mi] = (wm + mi * 32 + col) << 6;
#pragma unroll
    for (int ni = 0; ni < 2; ++ni) rowB[ni] = (wn + ni * 32 + col) << 6;
#pragma unroll
    for (int ks = 0; ks < 4; ++ks) slotv[ks] = ((ks * 2 + khalf) ^ (col & 7)) << 3;

    const float wsc = wscale_p[0];
    const float bsc = bscale_p[0];
    float badd[2];
#pragma unroll
    for (int ni = 0; ni < 2; ++ni)
        badd[ni] = bsc * rintf(bias[bn + wn + ni * 32 + col]);

    const int NT = K >> 6;

    // ---- prologue: stage tile 0 -> buf0 in deadline order
    // [Ab0, Ab2, Bb0, Bb1, Bb2, Bb3] needed at p0; [Ab1, Ab3] at p2.
    stage16(gA,                     sA);
    stage16(gA + (size_t)128 * K,   sA + 2 * 4096);
    stage16(gB,                     sB);
    stage16(gB + (size_t)64 * K,    sB + 1 * 4096);
    stage16(gB + (size_t)128 * K,   sB + 2 * 4096);
    stage16(gB + (size_t)192 * K,   sB + 3 * 4096);
    stage16(gA + (size_t)64 * K,    sA + 1 * 4096);
    stage16(gA + (size_t)192 * K,   sA + 3 * 4096);
    asm volatile("s_waitcnt vmcnt(2)" ::: "memory");   // first 6 landed
    __builtin_amdgcn_s_barrier();
    __builtin_amdgcn_sched_barrier(0);

    floatx16 acc[4][2] = {};

#define LDA_F(mi, ks) __builtin_bit_cast(bf16x8, *(const us8*)&SA[rowA[mi] + slotv[ks]])
#define LDB_F(ni, ks) __builtin_bit_cast(bf16x8, *(const us8*)&SB[rowB[ni] + slotv[ks]])

#define PH_BAR_LGKM()                                        \
    __builtin_amdgcn_s_barrier();                            \
    asm volatile("s_waitcnt lgkmcnt(0)" ::: "memory");       \
    __builtin_amdgcn_sched_barrier(0);

#define PH_MFMA(MIB, KSB)                                                     \
    __builtin_amdgcn_s_setprio(1);                                            \
    _Pragma("unroll") for (int k2 = 0; k2 < 2; ++k2)                          \
        _Pragma("unroll") for (int m2 = 0; m2 < 2; ++m2)                      \
            _Pragma("unroll") for (int ni = 0; ni < 2; ++ni)                  \
                acc[(MIB) + m2][ni] = __builtin_amdgcn_mfma_f32_32x32x16_bf16(\
                    Af[m2][k2], Bf[ni][(KSB) + k2], acc[(MIB) + m2][ni],      \
                    0, 0, 0);                                                 \
    __builtin_amdgcn_s_setprio(0);                                            \
    __builtin_amdgcn_sched_barrier(0);

    for (int t = 0; t < NT; ++t) {
        const unsigned short* SA = ldsA + (t & 1) * TILE;
        const unsigned short* SB = ldsB + (t & 1) * TILE;
        unsigned short* dA = sA + ((t + 1) & 1) * TILE;
        unsigned short* dB = sB + ((t + 1) & 1) * TILE;
        const size_t kt1 = (size_t)(t + 1) * BK;
        const bool st = (t + 1 < NT);

        bf16x8 Af[2][2];
        bf16x8 Bf[2][4];

        // ---- phase 0: A mi{0,1} ks{0,1}; B ks{0,1}; stage Ab0,Ab2,Bb0,Bb1
#pragma unroll
        for (int m2 = 0; m2 < 2; ++m2)
#pragma unroll
            for (int k2 = 0; k2 < 2; ++k2) Af[m2][k2] = LDA_F(m2, k2);
#pragma unroll
        for (int ni = 0; ni < 2; ++ni)
#pragma unroll
            for (int k2 = 0; k2 < 2; ++k2) Bf[ni][k2] = LDB_F(ni, k2);
        if (st) {
            stage16(gA + kt1,                   dA);
            stage16(gA + (size_t)128 * K + kt1, dA + 2 * 4096);
            stage16(gB + kt1,                   dB);
            stage16(gB + (size_t)64 * K + kt1,  dB + 1 * 4096);
        }
        PH_BAR_LGKM()
        PH_MFMA(0, 0)
        __builtin_amdgcn_s_barrier();
        __builtin_amdgcn_sched_barrier(0);

        // ---- phase 1: A mi{0,1} ks{2,3}; B ks{2,3}; stage Bb2,Bb3
#pragma unroll
        for (int m2 = 0; m2 < 2; ++m2)
#pragma unroll
            for (int k2 = 0; k2 < 2; ++k2) Af[m2][k2] = LDA_F(m2, 2 + k2);
#pragma unroll
        for (int ni = 0; ni < 2; ++ni)
#pragma unroll
            for (int k2 = 0; k2 < 2; ++k2) Bf[ni][2 + k2] = LDB_F(ni, 2 + k2);
        if (st) {
            stage16(gB + (size_t)128 * K + kt1, dB + 2 * 4096);
            stage16(gB + (size_t)192 * K + kt1, dB + 3 * 4096);
        }
        PH_BAR_LGKM()
        PH_MFMA(0, 2)
        // gate p2's reads of this tile's Ab1/Ab3 (staged at t-1 p3):
        // own newer stages = p0(4) + p1(2) = 6.
        asm volatile("s_waitcnt vmcnt(6)" ::: "memory");
        __builtin_amdgcn_s_barrier();
        __builtin_amdgcn_sched_barrier(0);

        // ---- phase 2: A mi{2,3} ks{0,1}; B regs reused; no stages
#pragma unroll
        for (int m2 = 0; m2 < 2; ++m2)
#pragma unroll
            for (int k2 = 0; k2 < 2; ++k2) Af[m2][k2] = LDA_F(2 + m2, k2);
        PH_BAR_LGKM()
        PH_MFMA(2, 0)
        __builtin_amdgcn_s_barrier();
        __builtin_amdgcn_sched_barrier(0);

        // ---- phase 3: A mi{2,3} ks{2,3}; stage Ab1,Ab3
#pragma unroll
        for (int m2 = 0; m2 < 2; ++m2)
#pragma unroll
            for (int k2 = 0; k2 < 2; ++k2) Af[m2][k2] = LDA_F(2 + m2, 2 + k2);
        if (st) {
            stage16(gA + (size_t)64 * K + kt1,  dA + 1 * 4096);
            stage16(gA + (size_t)192 * K + kt1, dA + 3 * 4096);
        }
        PH_BAR_LGKM()
        PH_MFMA(2, 2)
        // tile boundary: next tile's first-6 units must be landed; own
        // newest 2 (Ab1,Ab3 of t+1, just issued) may stay in flight.
        asm volatile("s_waitcnt vmcnt(2)" ::: "memory");
        __builtin_amdgcn_s_barrier();
        __builtin_amdgcn_sched_barrier(0);
    }

#undef LDA_F
#undef LDB_F
#undef PH_BAR_LGKM
#undef PH_MFMA

    // Epilogue. 32x32 C/D layout (m74/m101): col = lane&31,
    // row = (reg&3) + 8*(reg>>2) + 4*(lane>>5).
    const int rb = khalf << 2;
#pragma unroll
    for (int mi = 0; mi < 4; ++mi) {
#pragma unroll
        for (int ni = 0; ni < 2; ++ni) {
            const int n = bn + wn + ni * 32 + col;
#pragma unroll
            for (int reg = 0; reg < 16; ++reg) {
                const int m = bm + wm + mi * 32 + (reg & 3) + 8 * (reg >> 2) + rb;
                C[(size_t)m * N + n] = acc[mi][ni][reg] * wsc + badd[ni];
            }
        }
    }
}

// ---------------------------------------------------------------------------
// 128^2 kernel kept as fallback for shapes not divisible by 256.
// ---------------------------------------------------------------------------
__global__ __launch_bounds__(256) void gemm_bf16_bt(
    const unsigned short* __restrict__ A,
    const unsigned short* __restrict__ B,
    const float* __restrict__ bias,
    const float* __restrict__ wscale_p,
    const float* __restrict__ bscale_p,
    float* __restrict__ C,
    int M, int N, int K) {
    constexpr int BM = 128, BK = 64;
    __shared__ unsigned short ldsA[BM * BK];
    __shared__ unsigned short ldsB[BM * BK];

    const int tid  = threadIdx.x;
    const int wave = tid >> 6;
    const int lane = tid & 63;

    const int bm = blockIdx.y * BM;
    const int bn = blockIdx.x * BM;
    const int wm = (wave >> 1) * 64;
    const int wn = (wave & 1) * 64;

    const float wsc = wscale_p[0];
    const float bsc = bscale_p[0];

    const int col = lane & 31;
    const int khalf = lane >> 5;

    float badd[2];
#pragma unroll
    for (int ni = 0; ni < 2; ++ni)
        badd[ni] = bsc * rintf(bias[bn + wn + ni * 32 + col]);

    const int g_st = ((lane & 7) ^ (lane >> 3)) * 8;
    const unsigned short* gAp[4];
    const unsigned short* gBp[4];
    unsigned short* lA[4];
    unsigned short* lB[4];
#pragma unroll
    for (int i = 0; i < 4; ++i) {
        const int r = wave * 32 + i * 8 + (lane >> 3);
        gAp[i] = A + (size_t)(bm + r) * K + g_st;
        gBp[i] = B + (size_t)(bn + r) * K + g_st;
        lA[i] = &ldsA[(wave * 256 + i * 64) * 8];
        lB[i] = &ldsB[(wave * 256 + i * 64) * 8];
    }

    floatx16 acc[2][2] = {};

    for (int kt = 0; kt < K; kt += BK) {
#pragma unroll
        for (int i = 0; i < 4; ++i) {
            stage16(gAp[i] + kt, lA[i]);
            stage16(gBp[i] + kt, lB[i]);
        }
        __syncthreads();

#pragma unroll
        for (int ks = 0; ks < 4; ++ks) {
            const int gc = ks * 2 + khalf;
            const int slot = (gc ^ (lane & 7)) * 8;
            bf16x8 af[2], bfr[2];
#pragma unroll
            for (int mi = 0; mi < 2; ++mi) {
                const int off = (wm + mi * 32 + col) * BK + slot;
                af[mi] = __builtin_bit_cast(bf16x8, *(const us8*)&ldsA[off]);
            }
#pragma unroll
            for (int ni = 0; ni < 2; ++ni) {
                const int off = (wn + ni * 32 + col) * BK + slot;
                bfr[ni] = __builtin_bit_cast(bf16x8, *(const us8*)&ldsB[off]);
            }
#pragma unroll
            for (int mi = 0; mi < 2; ++mi)
#pragma unroll
                for (int ni = 0; ni < 2; ++ni)
                    acc[mi][ni] = __builtin_amdgcn_mfma_f32_32x32x16_bf16(
                        af[mi], bfr[ni], acc[mi][ni], 0, 0, 0);
        }
        __syncthreads();
    }

    const int rbase = 4 * khalf;
#pragma unroll
    for (int mi = 0; mi < 2; ++mi) {
#pragma unroll
        for (int ni = 0; ni < 2; ++ni) {
            const int n = bn + wn + ni * 32 + col;
#pragma unroll
            for (int reg = 0; reg < 16; ++reg) {
                const int m = bm + wm + mi * 32 + (reg & 3) + 8 * (reg >> 2) + rbase;
                C[(size_t)m * N + n] = acc[mi][ni][reg] * wsc + badd[ni];
            }
        }
    }
}

// ---------------------------------------------------------------------------
// Last-resort fallback (d_ws too small — not expected).
// ---------------------------------------------------------------------------
__global__ __launch_bounds__(256) void fallback_gemm(
    const float* __restrict__ A, const float* __restrict__ W,
    const float* __restrict__ bias, const float* __restrict__ wsp,
    const float* __restrict__ bsp, float* __restrict__ C, int M, int N, int K) {
    const int n = blockIdx.x * 256 + threadIdx.x;
    const int m = blockIdx.y;
    if (n >= N || m >= M) return;
    float s = 0.f;
    for (int k = 0; k < K; ++k)
        s += A[(size_t)m * K + k] * rintf(W[(size_t)n * K + k]);
    C[(size_t)m * N + n] = s * wsp[0] + bsp[0] * rintf(bias[n]);
}

extern "C" void kernel_launch(void* const* d_in, const int* in_sizes, int n_in,
                              void* d_out, int out_size, void* d_ws, size_t ws_size,
                              hipStream_t stream) {
    const float* input  = (const float*)d_in[0];
    const float* weight = (const float*)d_in[1];
    const float* bias   = (const float*)d_in[2];
    const float* wscale = (const float*)d_in[3];
    const float* bscale = (const float*)d_in[4];
    float* out = (float*)d_out;

    const int N = in_sizes[2];
    const int K = in_sizes[1] / N;
    const int M = in_sizes[0] / K;

    const size_t needA = (size_t)M * K * sizeof(unsigned short);
    const size_t needB = (size_t)N * K * sizeof(unsigned short);

    if (ws_size >= needA + needB && (M % 128) == 0 && (N % 128) == 0 &&
        (K % 64) == 0) {
        unsigned short* Abf = (unsigned short*)d_ws;
        unsigned short* Bbf = (unsigned short*)((char*)d_ws + needA);
        const long long nA4 = (long long)M * K / 4;
        const long long nB4 = (long long)N * K / 4;
        const long long nthr = nA4 + nB4;
        cvt_both<<<(unsigned)((nthr + 255) / 256), 256, 0, stream>>>(
            input, Abf, nA4, weight, Bbf, nB4);

        const int nwg256 = (M / 256) * (N / 256);
        if ((M % 256) == 0 && (N % 256) == 0 && (K / 64) >= 4 &&
            (nwg256 % 8) == 0) {
            gemm256_ph<<<dim3(nwg256), 512, 0, stream>>>(
                Abf, Bbf, bias, wscale, bscale, out, M, N, K);
        } else {
            dim3 grid(N / 128, M / 128);
            gemm_bf16_bt<<<grid, 256, 0, stream>>>(Abf, Bbf, bias, wscale,
                                                   bscale, out, M, N, K);
        }
    } else {
        dim3 grid((N + 255) / 256, M);
        fallback_gemm<<<grid, 256, 0, stream>>>(input, weight, bias, wscale, bscale, out, M, N, K);
    }
}